// Round 11
// baseline (2784.155 us; speedup 1.0000x reference)
//
#include <hip/hip_runtime.h>
#include <hip/hip_fp16.h>
#include <cmath>

#define VOCABSZ 50257
#define EMBD 512
#define HIDD 1024
#define CTXD 1024
#define SEQL 50
#define NSTEPS 50
#define BOS_ID 1
#define EOS_ID 2

#define NTHR 256
#define NB_GI 768               // gi blocks (3072 rows, 1 row/wave)
#define NB_WR 64                // logp writer blocks
#define NB_LOG 832              // logits stats blocks
#define NW_LOG (NB_LOG * 4)     // row stride (waves)
#define NB_GHN 192              // gh-next blocks in k_logits (4 rows/wave)
// k_logits block roles
#define KL_ATTN NB_LOG                  // 832
#define KL_GH0 (NB_LOG + 1)             // 833..1024
#define KL_WR0 (NB_LOG + 1 + NB_GHN)    // 1025..1088
#define KL_GRID (KL_WR0 + NB_WR)        // 1089
// k_pre grids
#define PRE_GRID NB_GI                  // 768 (in-loop: gi only)
#define PRE_GRID_FIN (NB_GI + NB_WR)    // 832 (epilogue: +64 logp writers)

#define LPAD 50304

// ws float offsets
#define OFF_M      0        // 50*1024 (M = enc @ Wa)
#define OFF_T      51200    // 64      (t_j = enc_j . ba)
#define OFF_H      51264    // 2*1024  (h_new(s) stored in buf (s+1)&1)
#define OFF_CTX    53312    // 1024
#define OFF_GI     54336    // 3072
#define OFF_GH     57408    // 2*3072  (gh(s) in buf s&1)
#define OFF_L      63552    // 2*50304 (logits of step s in buf s&1)
#define OFF_STATS  164160   // 832*8 (m,sum,v1,i1,v2,i2,pad,pad)
#define OFF_STATE  170816   // ints: emb[0..50] +0, done[0..50] +64; floats +128: logZ,+129 valid; ints +192: cnt[64]
#define OFF_WVH    171072   // fp16 Wv: 50257*1024 halves

__device__ __forceinline__ float wred_sum(float v) {
#pragma unroll
  for (int o = 32; o > 0; o >>= 1) v += __shfl_xor(v, o, 64);
  return v;
}

__device__ __forceinline__ float dot4(float4 a, float4 b) {
  return a.x * b.x + a.y * b.y + a.z * b.z + a.w * b.w;
}

__device__ __forceinline__ float wdot1024(const float* __restrict__ row, int lane,
                                          float4 b0, float4 b1, float4 b2, float4 b3) {
  const float4* r = (const float4*)row;
  float acc = dot4(r[lane], b0) + dot4(r[lane + 64], b1) +
              dot4(r[lane + 128], b2) + dot4(r[lane + 192], b3);
  return wred_sum(acc);
}

__device__ __forceinline__ bool beats(float v, int i, float v0, int i0) {
  return v > v0 || (v == v0 && i < i0);
}

__device__ __forceinline__ void top2_merge(float& v1, int& i1, float& v2, int& i2,
                                           float w1, int j1, float w2, int j2) {
  if (beats(w1, j1, v1, i1)) {
    float nv2; int ni2;
    if (beats(v1, i1, w2, j2)) { nv2 = v1; ni2 = i1; } else { nv2 = w2; ni2 = j2; }
    v1 = w1; i1 = j1; v2 = nv2; i2 = ni2;
  } else if (beats(w1, j1, v2, i2)) {
    v2 = w1; i2 = j1;
  }
}

__device__ __forceinline__ float acc8(uint4 a, const float* b) {
  const __half2* h = reinterpret_cast<const __half2*>(&a);
  float2 f0 = __half22float2(h[0]);
  float2 f1 = __half22float2(h[1]);
  float2 f2 = __half22float2(h[2]);
  float2 f3 = __half22float2(h[3]);
  return f0.x * b[0] + f0.y * b[1] + f1.x * b[2] + f1.y * b[3] +
         f2.x * b[4] + f2.y * b[5] + f3.x * b[6] + f3.y * b[7];
}

// ---------------- f32 -> f16 conversion (Wv) ----------------
__global__ void __launch_bounds__(NTHR)
k_cvt(const float4* __restrict__ src, uint2* __restrict__ dst, int n4) {
  int i = blockIdx.x * NTHR + threadIdx.x;
  const int stride = gridDim.x * NTHR;
  for (; i < n4; i += stride) {
    float4 v = src[i];
    __half2 a = __floats2half2_rn(v.x, v.y);
    __half2 b = __floats2half2_rn(v.z, v.w);
    uint2 u;
    u.x = *reinterpret_cast<unsigned*>(&a);
    u.y = *reinterpret_cast<unsigned*>(&b);
    dst[i] = u;
  }
}

// ---------------- K0a: M = enc @ Wa ----------------
__global__ void __launch_bounds__(1024)
k0_matM(float* __restrict__ ws, const float* __restrict__ enc,
        const float* __restrict__ Wa) {
  const int kc = blockIdx.x;
  const int jg = blockIdx.y;
  const int tid = threadIdx.x;
  const int w = tid >> 6, lane = tid & 63;
  const int jw = w & 3, q = w >> 2;
  const int j = jg * 4 + jw;
  const int k = kc * 64 + lane;
  __shared__ float s_red[16][64];
  float acc0 = 0.f, acc1 = 0.f, acc2 = 0.f, acc3 = 0.f;
  if (j < SEQL) {
    const float4* e4 = (const float4*)(enc + (size_t)j * CTXD);
    const float* Wc = Wa + k;
    for (int c4 = q * 64; c4 < q * 64 + 64; ++c4) {
      float4 e = e4[c4];
      const float* wp = Wc + (size_t)(c4 * 4) * HIDD;
      acc0 += e.x * wp[0];
      acc1 += e.y * wp[HIDD];
      acc2 += e.z * wp[2 * HIDD];
      acc3 += e.w * wp[3 * HIDD];
    }
  }
  s_red[w][lane] = acc0 + acc1 + acc2 + acc3;
  __syncthreads();
  if (q == 0 && j < SEQL) {
    float v = s_red[jw][lane] + s_red[4 + jw][lane] +
              s_red[8 + jw][lane] + s_red[12 + jw][lane];
    ws[OFF_M + (size_t)j * HIDD + k] = v;
  }
}

// ---------------- K0b: t = enc@ba, h0, state+counter init ----------------
__global__ void __launch_bounds__(NTHR)
k0_init(float* __restrict__ ws, const float* __restrict__ enc,
        const float* __restrict__ hid0, const float* __restrict__ Winit,
        const float* __restrict__ binit, const float* __restrict__ ba) {
  const int blk = blockIdx.x, tid = threadIdx.x;
  const int wave = tid >> 6, lane = tid & 63;
  if (blk == 0) {
    const float4* b4 = (const float4*)ba;
    float4 b0 = b4[lane], b1 = b4[lane + 64], b2 = b4[lane + 128], b3 = b4[lane + 192];
    for (int j = wave; j < SEQL; j += 4) {
      float v = wdot1024(enc + (size_t)j * CTXD, lane, b0, b1, b2, b3);
      if (lane == 0) ws[OFF_T + j] = v;
    }
    int* st = (int*)(ws + OFF_STATE);
    if (tid == 0) {
      st[0] = BOS_ID;  // emb[0]
      st[64] = 0;      // done[0]
    }
    if (tid < 64) st[192 + tid] = 0;  // per-step combine counters
  } else {
    const float4* h4 = (const float4*)hid0;
    float4 b0 = h4[lane], b1 = h4[lane + 64], b2 = h4[lane + 128], b3 = h4[lane + 192];
    int row = (blk - 1) * 4 + wave;
    float v = wdot1024(Winit + (size_t)row * CTXD, lane, b0, b1, b2, b3) + binit[row];
    if (lane == 0) ws[OFF_H + row] = v;  // h0 -> buf 0
  }
}

// ---------------- attention from ws[hoff] (one block) ----------------
__device__ __forceinline__ void attn_from(float* __restrict__ ws, int hoff,
                                          const float* __restrict__ enc,
                                          int tid, int wave, int lane,
                                          float* s_h, float* s_sc, float* s_aw) {
  ((float4*)s_h)[tid] = ((const float4*)(ws + hoff))[tid];
  __syncthreads();
  const float4* h4 = (const float4*)s_h;
  float4 b0 = h4[lane], b1 = h4[lane + 64], b2 = h4[lane + 128], b3 = h4[lane + 192];
  for (int j = wave; j < SEQL; j += 4) {
    float v = wdot1024(ws + OFF_M + (size_t)j * HIDD, lane, b0, b1, b2, b3) + ws[OFF_T + j];
    if (lane == 0) s_sc[j] = v;
  }
  __syncthreads();
  if (tid < 64) {
    float v = (tid < SEQL) ? s_sc[tid] : -INFINITY;
    float mx = v;
#pragma unroll
    for (int o = 32; o > 0; o >>= 1) mx = fmaxf(mx, __shfl_xor(mx, o, 64));
    float e = (tid < SEQL) ? expf(v - mx) : 0.f;
    float sm = wred_sum(e);
    if (tid < SEQL) s_aw[tid] = e / sm;
  }
  __syncthreads();
  const float4* enc4 = (const float4*)enc;
  float4 acc = make_float4(0.f, 0.f, 0.f, 0.f);
  for (int j = 0; j < SEQL; ++j) {
    float a = s_aw[j];
    float4 ev = enc4[(size_t)j * (CTXD / 4) + tid];
    acc.x += a * ev.x; acc.y += a * ev.y; acc.z += a * ev.z; acc.w += a * ev.w;
  }
  ((float4*)(ws + OFF_CTX))[tid] = acc;
}

// ---------------- K0c: ctx_0 + gh(0) into GH buf 0 ----------------
__global__ void __launch_bounds__(NTHR)
k_init2(float* __restrict__ ws, const float* __restrict__ enc,
        const float* __restrict__ Whh, const float* __restrict__ bhh) {
  const int blk = blockIdx.x, tid = threadIdx.x;
  const int wave = tid >> 6, lane = tid & 63;
  if (blk == 0) {
    __shared__ float s_h[HIDD];
    __shared__ float s_sc[64], s_aw[64];
    attn_from(ws, OFF_H, enc, tid, wave, lane, s_h, s_sc, s_aw);
  } else {
    const float4* h4 = (const float4*)(ws + OFF_H);
    float4 b0 = h4[lane], b1 = h4[lane + 64], b2 = h4[lane + 128], b3 = h4[lane + 192];
    const int r = (blk - 1) * 4 + wave;
    float v = wdot1024(Whh + (size_t)r * HIDD, lane, b0, b1, b2, b3) + bhh[r];
    if (lane == 0) ws[OFF_GH + r] = v;
  }
}

// ---------------- k_pre(s): gi(s) (in-loop) ; logp writers for s-1 (epilogue) ----------------
__global__ void __launch_bounds__(NTHR)
k_pre(float* __restrict__ ws, const float* __restrict__ E,
      const float* __restrict__ Wih, const float* __restrict__ bih,
      float* __restrict__ out, int s) {
  const int blk = blockIdx.x, tid = threadIdx.x;
  const int wave = tid >> 6, lane = tid & 63;
  const int* st_emb = (const int*)(ws + OFF_STATE);

  if (blk < NB_GI) {  // ---- gi rows for step s ----
    if (s >= NSTEPS) return;
    if (st_emb[64 + s]) return;  // done -> h frozen -> gi unused
    const int emb_s = st_emb[s];
    const int r = blk * 4 + wave;
    const float4* e4 = (const float4*)(E + (size_t)emb_s * EMBD);
    float4 eb0 = e4[lane], eb1 = e4[lane + 64];
    const float4* c4 = (const float4*)(ws + OFF_CTX);
    float4 cb0 = c4[lane], cb1 = c4[lane + 64], cb2 = c4[lane + 128], cb3 = c4[lane + 192];
    const float* rowp = Wih + (size_t)r * (EMBD + CTXD);
    const float4* re = (const float4*)rowp;
    const float4* rc = (const float4*)(rowp + EMBD);
    float acc = dot4(re[lane], eb0) + dot4(re[lane + 64], eb1) +
                dot4(rc[lane], cb0) + dot4(rc[lane + 64], cb1) +
                dot4(rc[lane + 128], cb2) + dot4(rc[lane + 192], cb3);
    float v = wred_sum(acc) + bih[r];
    if (lane == 0) ws[OFF_GI + r] = v;
  } else {  // ---- epilogue logp writers for step s-1 ----
    if (s == 0) return;
    const float logZ = ws[OFF_STATE + 128];
    const bool valid = ws[OFF_STATE + 129] != 0.f;
    const float* Lp = ws + OFF_L + (size_t)((s - 1) & 1) * LPAD;
    float* logp = out + NSTEPS + (size_t)(s - 1) * VOCABSZ;
    for (int i = (blk - NB_GI) * NTHR + tid; i < VOCABSZ; i += NB_WR * NTHR)
      logp[i] = valid ? (Lp[i] - logZ) : 0.f;
  }
}

// ---------------- k_logits(s): GRU; fp16 GEMV + stats; last-block combine -> state/outputs;
//                  attn(s+1); gh(s+1); logp(s-1) writers ----------------
__global__ void __launch_bounds__(NTHR)
k_logits(float* __restrict__ ws, const float* __restrict__ Wv,
         const float* __restrict__ bv, const float* __restrict__ enc,
         const float* __restrict__ Whh, const float* __restrict__ bhh,
         float* __restrict__ out, int s) {
  const int blk = blockIdx.x, tid = threadIdx.x;
  const int wave = tid >> 6, lane = tid & 63;
  const int p = s & 1, np = p ^ 1;

  // ---- logp writers for step s-1 (no GRU needed) ----
  if (blk >= KL_WR0) {
    if (s == 0) return;
    const float logZ = ws[OFF_STATE + 128];
    const bool valid = ws[OFF_STATE + 129] != 0.f;
    const float* Lp = ws + OFF_L + (size_t)np * LPAD;  // (s-1)&1 == np
    float* logp = out + NSTEPS + (size_t)(s - 1) * VOCABSZ;
    for (int i = (blk - KL_WR0) * NTHR + tid; i < VOCABSZ; i += NB_WR * NTHR)
      logp[i] = valid ? (Lp[i] - logZ) : 0.f;
    return;
  }

  __shared__ float s_h[HIDD];
  int* st_emb = (int*)(ws + OFF_STATE);
  int* st_done = st_emb + 64;
  const int done = st_done[s];

  // fused pointwise GRU (redundant per block): h_new(s) from h_new(s-1), gi(s), gh(s)
  const float* hp = ws + OFF_H + p * HIDD;
  const float* ghp = ws + OFF_GH + p * 3 * HIDD;
#pragma unroll
  for (int it = 0; it < HIDD / NTHR; ++it) {
    const int i = tid + it * NTHR;
    float h = hp[i];
    if (done) {
      s_h[i] = h;
    } else {
      float r = 1.f / (1.f + __expf(-(ws[OFF_GI + i] + ghp[i])));
      float z = 1.f / (1.f + __expf(-(ws[OFF_GI + HIDD + i] + ghp[HIDD + i])));
      float n = tanhf(ws[OFF_GI + 2 * HIDD + i] + r * ghp[2 * HIDD + i]);
      s_h[i] = (1.f - z) * n + z * h;
    }
  }
  __syncthreads();
  if (blk == 0) {  // persist h_new(s) -> buf np ; done-path state publish
    ((float4*)(ws + OFF_H + np * HIDD))[tid] = ((const float4*)s_h)[tid];
    if (done && tid == 0) {
      out[s] = -1.f;
      out[NSTEPS + (size_t)NSTEPS * VOCABSZ + s] = 0.f;
      ws[OFF_STATE + 128] = 0.f;
      ws[OFF_STATE + 129] = 0.f;
      st_emb[s + 1] = st_emb[s];
      st_done[s + 1] = 1;
    }
  }

  if (blk >= KL_GH0) {  // ---- gh(s+1) -> GH buf np ----
    if (s + 1 >= NSTEPS || done) return;
    const float4* h4 = (const float4*)s_h;
    float4 b0 = h4[lane], b1 = h4[lane + 64], b2 = h4[lane + 128], b3 = h4[lane + 192];
    const int wid = (blk - KL_GH0) * 4 + wave;
#pragma unroll
    for (int k = 0; k < 4; ++k) {
      const int r = wid + 768 * k;
      float v = wdot1024(Whh + (size_t)r * HIDD, lane, b0, b1, b2, b3) + bhh[r];
      if (lane == 0) ws[OFF_GH + np * 3 * HIDD + r] = v;
    }
    return;
  }

  if (blk == KL_ATTN) {  // ---- attn for step s+1 ----
    if (s + 1 >= NSTEPS || done) return;
    __shared__ float s_sc[64], s_aw[64];
    const float4* h4 = (const float4*)s_h;
    float4 b0 = h4[lane], b1 = h4[lane + 64], b2 = h4[lane + 128], b3 = h4[lane + 192];
    for (int j = wave; j < SEQL; j += 4) {
      float v = wdot1024(ws + OFF_M + (size_t)j * HIDD, lane, b0, b1, b2, b3) + ws[OFF_T + j];
      if (lane == 0) s_sc[j] = v;
    }
    __syncthreads();
    if (tid < 64) {
      float v = (tid < SEQL) ? s_sc[tid] : -INFINITY;
      float mx = v;
#pragma unroll
      for (int o = 32; o > 0; o >>= 1) mx = fmaxf(mx, __shfl_xor(mx, o, 64));
      float e = (tid < SEQL) ? expf(v - mx) : 0.f;
      float smv = wred_sum(e);
      if (tid < SEQL) s_aw[tid] = e / smv;
    }
    __syncthreads();
    const float4* enc4 = (const float4*)enc;
    float4 acc = make_float4(0.f, 0.f, 0.f, 0.f);
    for (int j = 0; j < SEQL; ++j) {
      float a = s_aw[j];
      float4 ev = enc4[(size_t)j * (CTXD / 4) + tid];
      acc.x += a * ev.x; acc.y += a * ev.y; acc.z += a * ev.z; acc.w += a * ev.w;
    }
    ((float4*)(ws + OFF_CTX))[tid] = acc;
    return;
  }

  // ---- fp16 logits GEMV + per-wave online stats (m, sum, top-2) ----
  if (done) return;  // blk 0 published frozen state above
  __shared__ float sm[4], ssm[4], sv1[4], sv2[4];
  __shared__ int si1[4], si2[4];
  __shared__ int s_last;
  float hb[16];
  {
    const float4* h4 = (const float4*)s_h;
    float4 a = h4[lane * 2], b = h4[lane * 2 + 1];
    float4 c = h4[128 + lane * 2], d = h4[129 + lane * 2];
    hb[0] = a.x; hb[1] = a.y; hb[2] = a.z; hb[3] = a.w;
    hb[4] = b.x; hb[5] = b.y; hb[6] = b.z; hb[7] = b.w;
    hb[8] = c.x; hb[9] = c.y; hb[10] = c.z; hb[11] = c.w;
    hb[12] = d.x; hb[13] = d.y; hb[14] = d.z; hb[15] = d.w;
  }
  const __half* WvH = (const __half*)(ws + OFF_WVH);
  float* Lc = ws + OFF_L + (size_t)p * LPAD;
  float m = -INFINITY, sum = 0.f, v1 = -INFINITY, v2 = -INFINITY;
  int i1 = 0x7fffffff, i2 = 0x7fffffff;
  for (int row = blk * 4 + wave; row < VOCABSZ; row += NW_LOG) {
    const uint4* r4 = (const uint4*)(WvH + (size_t)row * HIDD);
    float acc = acc8(r4[lane], hb) + acc8(r4[lane + 64], hb + 8);
    float l = wred_sum(acc) + bv[row];
    if (lane == 0) Lc[row] = l;
    float mn = fmaxf(m, l);
    sum = ((m == -INFINITY) ? 0.f : sum * __expf(m - mn)) + __expf(l - mn);
    m = mn;
    if (beats(l, row, v1, i1)) { v2 = v1; i2 = i1; v1 = l; i1 = row; }
    else if (beats(l, row, v2, i2)) { v2 = l; i2 = row; }
  }
  if (lane == 0) {
    sm[wave] = m; ssm[wave] = sum;
    sv1[wave] = v1; si1[wave] = i1; sv2[wave] = v2; si2[wave] = i2;
  }
  __syncthreads();
  if (tid == 0) {
    float mm = sm[0], su = ssm[0], a1 = sv1[0], a2 = sv2[0];
    int b1 = si1[0], b2 = si2[0];
#pragma unroll
    for (int w = 1; w < 4; ++w) {
      float mn = fmaxf(mm, sm[w]);
      su = su * __expf(mm - mn) + ssm[w] * __expf(sm[w] - mn);
      mm = mn;
      top2_merge(a1, b1, a2, b2, sv1[w], si1[w], sv2[w], si2[w]);
    }
    float* st = ws + OFF_STATS + (size_t)blk * 8;
    st[0] = mm; st[1] = su;
    st[2] = a1; st[3] = __int_as_float(b1);
    st[4] = a2; st[5] = __int_as_float(b2);
    __threadfence();
    int old = atomicAdd((int*)(ws + OFF_STATE) + 192 + s, 1);
    s_last = (old == NB_LOG - 1) ? 1 : 0;
  }
  __syncthreads();
  if (!s_last) return;

  // ---- last block: deterministic combine of all 832 records ----
  __threadfence();
  __shared__ float rm[NTHR], rs_[NTHR], rv1[NTHR], rv2[NTHR];
  __shared__ int ri1[NTHR], ri2[NTHR];
  __shared__ float s_ex[2];
  {
    float cm = -INFINITY, cs = 0.f, c1 = -INFINITY, c2 = -INFINITY;
    int ci1 = 0x7fffffff, ci2 = 0x7fffffff;
    volatile const float* sb = ws + OFF_STATS;
    for (int q = tid; q < NB_LOG; q += NTHR) {
      const volatile float* st = sb + (size_t)q * 8;
      float A0 = st[0], A1 = st[1], A2 = st[2], A3 = st[3], A4 = st[4], A5 = st[5];
      float mn = fmaxf(cm, A0);
      cs = ((cm == -INFINITY) ? 0.f : cs * __expf(cm - mn)) + A1 * __expf(A0 - mn);
      cm = mn;
      top2_merge(c1, ci1, c2, ci2, A2, __float_as_int(A3), A4, __float_as_int(A5));
    }
    rm[tid] = cm; rs_[tid] = cs; rv1[tid] = c1; ri1[tid] = ci1; rv2[tid] = c2; ri2[tid] = ci2;
  }
  __syncthreads();
  for (int st = 128; st > 0; st >>= 1) {
    if (tid < st) {
      float m2 = rm[tid + st], s2 = rs_[tid + st];
      float mn = fmaxf(rm[tid], m2);
      rs_[tid] = rs_[tid] * __expf(rm[tid] - mn) + s2 * __expf(m2 - mn);
      rm[tid] = mn;
      float a1 = rv1[tid], a2 = rv2[tid];
      int b1 = ri1[tid], b2 = ri2[tid];
      top2_merge(a1, b1, a2, b2, rv1[tid + st], ri1[tid + st], rv2[tid + st], ri2[tid + st]);
      rv1[tid] = a1; ri1[tid] = b1; rv2[tid] = a2; ri2[tid] = b2;
    }
    __syncthreads();
  }
  const int fi1 = ri1[0], fi2 = ri2[0];
  // exact f32 recompute of the two candidates (fp16 argmax protection)
  if (wave < 2) {
    const float4* h4 = (const float4*)s_h;
    float4 b0 = h4[lane], b1 = h4[lane + 64], b2 = h4[lane + 128], b3 = h4[lane + 192];
    const int r = (wave == 0) ? fi1 : fi2;
    float v = wdot1024(Wv + (size_t)r * HIDD, lane, b0, b1, b2, b3) + bv[r];
    if (lane == 0) s_ex[wave] = v;
  }
  __syncthreads();
  if (tid == 0) {
    const int gidx = beats(s_ex[1], fi2, s_ex[0], fi1) ? fi2 : fi1;
    const float logZ = rm[0] + logf(rs_[0]);
    const bool eos = (gidx == EOS_ID);
    out[s] = eos ? -1.f : (float)gidx;                       // valid==true here
    out[NSTEPS + (size_t)NSTEPS * VOCABSZ + s] = 1.f;
    ws[OFF_STATE + 128] = logZ;
    ws[OFF_STATE + 129] = 1.f;
    st_emb[s + 1] = eos ? st_emb[s] : gidx;
    st_done[s + 1] = eos ? 1 : 0;
  }
}

extern "C" void kernel_launch(void* const* d_in, const int* in_sizes, int n_in,
                              void* d_out, int out_size, void* d_ws, size_t ws_size,
                              hipStream_t stream) {
  const float* enc   = (const float*)d_in[0];
  const float* hid0  = (const float*)d_in[1];
  const float* E     = (const float*)d_in[2];
  const float* Winit = (const float*)d_in[3];
  const float* binit = (const float*)d_in[4];
  const float* Wa    = (const float*)d_in[5];
  const float* ba    = (const float*)d_in[6];
  const float* Wih   = (const float*)d_in[7];
  const float* Whh   = (const float*)d_in[8];
  const float* bih   = (const float*)d_in[9];
  const float* bhh   = (const float*)d_in[10];
  const float* Wv    = (const float*)d_in[11];
  const float* bv    = (const float*)d_in[12];
  float* out = (float*)d_out;
  float* ws  = (float*)d_ws;

  const int n4 = (VOCABSZ * HIDD) / 4;
  k_cvt<<<4096, NTHR, 0, stream>>>((const float4*)Wv, (uint2*)(ws + OFF_WVH), n4);
  k0_matM<<<dim3(16, 13), 1024, 0, stream>>>(ws, enc, Wa);
  k0_init<<<257, NTHR, 0, stream>>>(ws, enc, hid0, Winit, binit, ba);
  k_init2<<<769, NTHR, 0, stream>>>(ws, enc, Whh, bhh);
  for (int s = 0; s < NSTEPS; ++s) {
    k_pre<<<PRE_GRID, NTHR, 0, stream>>>(ws, E, Wih, bih, out, s);
    k_logits<<<KL_GRID, NTHR, 0, stream>>>(ws, Wv, bv, enc, Whh, bhh, out, s);
  }
  k_pre<<<PRE_GRID_FIN, NTHR, 0, stream>>>(ws, E, Wih, bih, out, NSTEPS);
}

// Round 12
// 2086.499 us; speedup vs baseline: 1.3344x; 1.3344x over previous
//
#include <hip/hip_runtime.h>
#include <hip/hip_fp16.h>
#include <cmath>

#define VOCABSZ 50257
#define EMBD 512
#define HIDD 1024
#define CTXD 1024
#define SEQL 50
#define NSTEPS 50
#define BOS_ID 1
#define EOS_ID 2

#define NTHR 256
#define NB_GI 768               // gi blocks (3072 rows, 1 row/wave)
#define NB_WR 64                // logp writer blocks
#define NB_LOG 1664             // logits stats blocks (2x R9: concurrency probe)
#define NW_LOG (NB_LOG * 4)     // row stride (waves)
#define NB_GHN 192              // gh-next blocks in k_logits (4 rows/wave)
// k_logits block roles
#define KL_ATTN NB_LOG                  // 1664
#define KL_GH0 (NB_LOG + 1)             // 1665..1856
#define KL_WR0 (NB_LOG + 1 + NB_GHN)    // 1857..1920
#define KL_GRID (KL_WR0 + NB_WR)        // 1921
// k_pre grids
#define PRE_GRID (NB_GI + 1)            // 769 (in-loop)
#define PRE_GRID_FIN (NB_GI + 1 + NB_WR)// 833 (epilogue)

#define LPAD 50304

// ws float offsets
#define OFF_M      0        // 50*1024 (M = enc @ Wa)
#define OFF_T      51200    // 64      (t_j = enc_j . ba)
#define OFF_H      51264    // 2*1024  (h_new(s) stored in buf (s+1)&1)
#define OFF_CTX    53312    // 1024
#define OFF_GI     54336    // 3072
#define OFF_GH     57408    // 2*3072  (gh(s) in buf s&1)
#define OFF_L      63552    // 2*50304 (logits of step s in buf s&1)
#define OFF_STATS  164160   // 1664*8 (m,sum,v1,i1,v2,i2,pad,pad) = 13312
#define OFF_STATE  177472   // ints: emb[0..50] +0, done[0..50] +64; floats +128: logZ, +129 valid
#define OFF_WVH    177728   // fp16 Wv: 50257*1024 halves

__device__ __forceinline__ float wred_sum(float v) {
#pragma unroll
  for (int o = 32; o > 0; o >>= 1) v += __shfl_xor(v, o, 64);
  return v;
}

__device__ __forceinline__ float dot4(float4 a, float4 b) {
  return a.x * b.x + a.y * b.y + a.z * b.z + a.w * b.w;
}

__device__ __forceinline__ float wdot1024(const float* __restrict__ row, int lane,
                                          float4 b0, float4 b1, float4 b2, float4 b3) {
  const float4* r = (const float4*)row;
  float acc = dot4(r[lane], b0) + dot4(r[lane + 64], b1) +
              dot4(r[lane + 128], b2) + dot4(r[lane + 192], b3);
  return wred_sum(acc);
}

__device__ __forceinline__ bool beats(float v, int i, float v0, int i0) {
  return v > v0 || (v == v0 && i < i0);
}

__device__ __forceinline__ void top2_merge(float& v1, int& i1, float& v2, int& i2,
                                           float w1, int j1, float w2, int j2) {
  if (beats(w1, j1, v1, i1)) {
    float nv2; int ni2;
    if (beats(v1, i1, w2, j2)) { nv2 = v1; ni2 = i1; } else { nv2 = w2; ni2 = j2; }
    v1 = w1; i1 = j1; v2 = nv2; i2 = ni2;
  } else if (beats(w1, j1, v2, i2)) {
    v2 = w1; i2 = j1;
  }
}

__device__ __forceinline__ float acc8(uint4 a, const float* b) {
  const __half2* h = reinterpret_cast<const __half2*>(&a);
  float2 f0 = __half22float2(h[0]);
  float2 f1 = __half22float2(h[1]);
  float2 f2 = __half22float2(h[2]);
  float2 f3 = __half22float2(h[3]);
  return f0.x * b[0] + f0.y * b[1] + f1.x * b[2] + f1.y * b[3] +
         f2.x * b[4] + f2.y * b[5] + f3.x * b[6] + f3.y * b[7];
}

// ---------------- f32 -> f16 conversion (Wv) ----------------
__global__ void __launch_bounds__(NTHR)
k_cvt(const float4* __restrict__ src, uint2* __restrict__ dst, int n4) {
  int i = blockIdx.x * NTHR + threadIdx.x;
  const int stride = gridDim.x * NTHR;
  for (; i < n4; i += stride) {
    float4 v = src[i];
    __half2 a = __floats2half2_rn(v.x, v.y);
    __half2 b = __floats2half2_rn(v.z, v.w);
    uint2 u;
    u.x = *reinterpret_cast<unsigned*>(&a);
    u.y = *reinterpret_cast<unsigned*>(&b);
    dst[i] = u;
  }
}

// ---------------- K0a: M = enc @ Wa ----------------
__global__ void __launch_bounds__(1024)
k0_matM(float* __restrict__ ws, const float* __restrict__ enc,
        const float* __restrict__ Wa) {
  const int kc = blockIdx.x;
  const int jg = blockIdx.y;
  const int tid = threadIdx.x;
  const int w = tid >> 6, lane = tid & 63;
  const int jw = w & 3, q = w >> 2;
  const int j = jg * 4 + jw;
  const int k = kc * 64 + lane;
  __shared__ float s_red[16][64];
  float acc0 = 0.f, acc1 = 0.f, acc2 = 0.f, acc3 = 0.f;
  if (j < SEQL) {
    const float4* e4 = (const float4*)(enc + (size_t)j * CTXD);
    const float* Wc = Wa + k;
    for (int c4 = q * 64; c4 < q * 64 + 64; ++c4) {
      float4 e = e4[c4];
      const float* wp = Wc + (size_t)(c4 * 4) * HIDD;
      acc0 += e.x * wp[0];
      acc1 += e.y * wp[HIDD];
      acc2 += e.z * wp[2 * HIDD];
      acc3 += e.w * wp[3 * HIDD];
    }
  }
  s_red[w][lane] = acc0 + acc1 + acc2 + acc3;
  __syncthreads();
  if (q == 0 && j < SEQL) {
    float v = s_red[jw][lane] + s_red[4 + jw][lane] +
              s_red[8 + jw][lane] + s_red[12 + jw][lane];
    ws[OFF_M + (size_t)j * HIDD + k] = v;
  }
}

// ---------------- K0b: t = enc@ba, h0, state init ----------------
__global__ void __launch_bounds__(NTHR)
k0_init(float* __restrict__ ws, const float* __restrict__ enc,
        const float* __restrict__ hid0, const float* __restrict__ Winit,
        const float* __restrict__ binit, const float* __restrict__ ba) {
  const int blk = blockIdx.x, tid = threadIdx.x;
  const int wave = tid >> 6, lane = tid & 63;
  if (blk == 0) {
    const float4* b4 = (const float4*)ba;
    float4 b0 = b4[lane], b1 = b4[lane + 64], b2 = b4[lane + 128], b3 = b4[lane + 192];
    for (int j = wave; j < SEQL; j += 4) {
      float v = wdot1024(enc + (size_t)j * CTXD, lane, b0, b1, b2, b3);
      if (lane == 0) ws[OFF_T + j] = v;
    }
    if (tid == 0) {
      int* st_emb = (int*)(ws + OFF_STATE);
      st_emb[0] = BOS_ID;
      st_emb[64] = 0;  // done[0]
    }
  } else {
    const float4* h4 = (const float4*)hid0;
    float4 b0 = h4[lane], b1 = h4[lane + 64], b2 = h4[lane + 128], b3 = h4[lane + 192];
    int row = (blk - 1) * 4 + wave;
    float v = wdot1024(Winit + (size_t)row * CTXD, lane, b0, b1, b2, b3) + binit[row];
    if (lane == 0) ws[OFF_H + row] = v;  // h0 -> buf 0
  }
}

// ---------------- attention from ws[hoff] (one block) ----------------
__device__ __forceinline__ void attn_from(float* __restrict__ ws, int hoff,
                                          const float* __restrict__ enc,
                                          int tid, int wave, int lane,
                                          float* s_h, float* s_sc, float* s_aw) {
  ((float4*)s_h)[tid] = ((const float4*)(ws + hoff))[tid];
  __syncthreads();
  const float4* h4 = (const float4*)s_h;
  float4 b0 = h4[lane], b1 = h4[lane + 64], b2 = h4[lane + 128], b3 = h4[lane + 192];
  for (int j = wave; j < SEQL; j += 4) {
    float v = wdot1024(ws + OFF_M + (size_t)j * HIDD, lane, b0, b1, b2, b3) + ws[OFF_T + j];
    if (lane == 0) s_sc[j] = v;
  }
  __syncthreads();
  if (tid < 64) {
    float v = (tid < SEQL) ? s_sc[tid] : -INFINITY;
    float mx = v;
#pragma unroll
    for (int o = 32; o > 0; o >>= 1) mx = fmaxf(mx, __shfl_xor(mx, o, 64));
    float e = (tid < SEQL) ? expf(v - mx) : 0.f;
    float sm = wred_sum(e);
    if (tid < SEQL) s_aw[tid] = e / sm;
  }
  __syncthreads();
  const float4* enc4 = (const float4*)enc;
  float4 acc = make_float4(0.f, 0.f, 0.f, 0.f);
  for (int j = 0; j < SEQL; ++j) {
    float a = s_aw[j];
    float4 ev = enc4[(size_t)j * (CTXD / 4) + tid];
    acc.x += a * ev.x; acc.y += a * ev.y; acc.z += a * ev.z; acc.w += a * ev.w;
  }
  ((float4*)(ws + OFF_CTX))[tid] = acc;
}

// ---------------- K0c: ctx_0 + gh(0) into GH buf 0 ----------------
__global__ void __launch_bounds__(NTHR)
k_init2(float* __restrict__ ws, const float* __restrict__ enc,
        const float* __restrict__ Whh, const float* __restrict__ bhh) {
  const int blk = blockIdx.x, tid = threadIdx.x;
  const int wave = tid >> 6, lane = tid & 63;
  if (blk == 0) {
    __shared__ float s_h[HIDD];
    __shared__ float s_sc[64], s_aw[64];
    attn_from(ws, OFF_H, enc, tid, wave, lane, s_h, s_sc, s_aw);
  } else {
    const float4* h4 = (const float4*)(ws + OFF_H);
    float4 b0 = h4[lane], b1 = h4[lane + 64], b2 = h4[lane + 128], b3 = h4[lane + 192];
    const int r = (blk - 1) * 4 + wave;
    float v = wdot1024(Whh + (size_t)r * HIDD, lane, b0, b1, b2, b3) + bhh[r];
    if (lane == 0) ws[OFF_GH + r] = v;
  }
}

// ---------------- k_pre(s): combine stats(s-1) -> state/outputs; gi(s) ----------------
__global__ void __launch_bounds__(NTHR)
k_pre(float* __restrict__ ws, const float* __restrict__ E,
      const float* __restrict__ Wih, const float* __restrict__ bih,
      const float* __restrict__ Wv, const float* __restrict__ bv,
      float* __restrict__ out, int s) {
  const int blk = blockIdx.x, tid = threadIdx.x;
  const int wave = tid >> 6, lane = tid & 63;
  int* st_emb = (int*)(ws + OFF_STATE);
  int* st_done = st_emb + 64;
  const int hoff = OFF_H + (s & 1) * HIDD;  // h_new(s-1)

  const bool is_gi = (blk < NB_GI);
  const bool is_state = (blk == NB_GI);
  const bool is_writer = (blk > NB_GI);
  if (is_gi && s >= NSTEPS) return;
  if ((is_state || is_writer) && s == 0) return;

  int emb_s = 0, D_s = 0, gidx = -1;
  float logZ = 0.f;
  bool valid = false, eos = false;

  if (s > 0) {
    __shared__ float rm[NTHR], rs_[NTHR], rv1[NTHR], rv2[NTHR];
    __shared__ int ri1[NTHR], ri2[NTHR];
    __shared__ float s_ex[2];
    float m = -INFINITY, su = 0.f, v1 = -INFINITY, v2 = -INFINITY;
    int i1 = 0x7fffffff, i2 = 0x7fffffff;
    const float4* sb = (const float4*)(ws + OFF_STATS);
    for (int q = tid; q < NB_LOG; q += NTHR) {
      float4 A = sb[q * 2];
      float4 B = sb[q * 2 + 1];
      float mn = fmaxf(m, A.x);
      su = ((m == -INFINITY) ? 0.f : su * __expf(m - mn)) + A.y * __expf(A.x - mn);
      m = mn;
      top2_merge(v1, i1, v2, i2, A.z, __float_as_int(A.w), B.x, __float_as_int(B.y));
    }
    rm[tid] = m; rs_[tid] = su; rv1[tid] = v1; ri1[tid] = i1; rv2[tid] = v2; ri2[tid] = i2;
    __syncthreads();
    for (int st = 128; st > 0; st >>= 1) {
      if (tid < st) {
        float m2 = rm[tid + st], s2 = rs_[tid + st];
        float mn = fmaxf(rm[tid], m2);
        rs_[tid] = rs_[tid] * __expf(rm[tid] - mn) + s2 * __expf(m2 - mn);
        rm[tid] = mn;
        float a1 = rv1[tid], a2 = rv2[tid];
        int b1 = ri1[tid], b2 = ri2[tid];
        top2_merge(a1, b1, a2, b2, rv1[tid + st], ri1[tid + st], rv2[tid + st], ri2[tid + st]);
        rv1[tid] = a1; ri1[tid] = b1; rv2[tid] = a2; ri2[tid] = b2;
      }
      __syncthreads();
    }
    const int fi1 = ri1[0], fi2 = ri2[0];
    // exact f32 recompute of the two candidates (fp16 argmax protection)
    if (wave < 2) {
      const float4* h4 = (const float4*)(ws + hoff);
      float4 b0 = h4[lane], b1 = h4[lane + 64], b2 = h4[lane + 128], b3 = h4[lane + 192];
      const int r = (wave == 0) ? fi1 : fi2;
      float v = wdot1024(Wv + (size_t)r * HIDD, lane, b0, b1, b2, b3) + bv[r];
      if (lane == 0) s_ex[wave] = v;
    }
    __syncthreads();
    gidx = beats(s_ex[1], fi2, s_ex[0], fi1) ? fi2 : fi1;
    logZ = rm[0] + logf(rs_[0]);
    const int Dp = st_done[s - 1];
    valid = (Dp == 0);
    eos = (gidx == EOS_ID);
    D_s = Dp | (eos ? 1 : 0);
    emb_s = (valid && !eos) ? gidx : st_emb[s - 1];
  } else {
    emb_s = st_emb[0];
  }

  if (is_gi) {
    if (D_s) return;  // h frozen -> gi unused
    const int r = blk * 4 + wave;
    const float4* e4 = (const float4*)(E + (size_t)emb_s * EMBD);
    float4 eb0 = e4[lane], eb1 = e4[lane + 64];
    const float4* c4 = (const float4*)(ws + OFF_CTX);
    float4 cb0 = c4[lane], cb1 = c4[lane + 64], cb2 = c4[lane + 128], cb3 = c4[lane + 192];
    const float* rowp = Wih + (size_t)r * (EMBD + CTXD);
    const float4* re = (const float4*)rowp;
    const float4* rc = (const float4*)(rowp + EMBD);
    float acc = dot4(re[lane], eb0) + dot4(re[lane + 64], eb1) +
                dot4(rc[lane], cb0) + dot4(rc[lane + 64], cb1) +
                dot4(rc[lane + 128], cb2) + dot4(rc[lane + 192], cb3);
    float v = wred_sum(acc) + bih[r];
    if (lane == 0) ws[OFF_GI + r] = v;
  } else if (is_state) {
    if (tid == 0) {
      out[s - 1] = (valid && !eos) ? (float)gidx : -1.f;
      out[NSTEPS + (size_t)NSTEPS * VOCABSZ + (s - 1)] = valid ? 1.f : 0.f;
      st_emb[s] = emb_s;
      st_done[s] = D_s;
      ws[OFF_STATE + 128] = logZ;
      ws[OFF_STATE + 129] = valid ? 1.f : 0.f;
    }
  } else {  // epilogue logp writers for step s-1
    const float* Lp = ws + OFF_L + (size_t)((s - 1) & 1) * LPAD;
    float* logp = out + NSTEPS + (size_t)(s - 1) * VOCABSZ;
    for (int i = (blk - NB_GI - 1) * NTHR + tid; i < VOCABSZ; i += NB_WR * NTHR)
      logp[i] = valid ? (Lp[i] - logZ) : 0.f;
  }
}

// ---------------- k_logits(s): GRU -> h_new(s); fp16 GEMV + stats; attn; gh; logp(s-1) writers ----------------
__global__ void __launch_bounds__(NTHR)
k_logits(float* __restrict__ ws, const float* __restrict__ bv,
         const float* __restrict__ enc, const float* __restrict__ Whh,
         const float* __restrict__ bhh, float* __restrict__ out, int s) {
  const int blk = blockIdx.x, tid = threadIdx.x;
  const int wave = tid >> 6, lane = tid & 63;
  const int p = s & 1, np = p ^ 1;

  // ---- logp writers for step s-1 (no GRU needed) ----
  if (blk >= KL_WR0) {
    if (s == 0) return;
    const float logZ = ws[OFF_STATE + 128];
    const bool valid = ws[OFF_STATE + 129] != 0.f;
    const float* Lp = ws + OFF_L + (size_t)np * LPAD;  // (s-1)&1 == np
    float* logp = out + NSTEPS + (size_t)(s - 1) * VOCABSZ;
    for (int i = (blk - KL_WR0) * NTHR + tid; i < VOCABSZ; i += NB_WR * NTHR)
      logp[i] = valid ? (Lp[i] - logZ) : 0.f;
    return;
  }

  __shared__ float s_h[HIDD];
  const int* st_emb = (const int*)(ws + OFF_STATE);
  const int done = st_emb[64 + s];

  // fused pointwise GRU (redundant per block): h_new(s) from h_new(s-1), gi(s), gh(s)
  const float* hp = ws + OFF_H + p * HIDD;
  const float* ghp = ws + OFF_GH + p * 3 * HIDD;
#pragma unroll
  for (int it = 0; it < HIDD / NTHR; ++it) {
    const int i = tid + it * NTHR;
    float h = hp[i];
    if (done) {
      s_h[i] = h;
    } else {
      float r = 1.f / (1.f + __expf(-(ws[OFF_GI + i] + ghp[i])));
      float z = 1.f / (1.f + __expf(-(ws[OFF_GI + HIDD + i] + ghp[HIDD + i])));
      float n = tanhf(ws[OFF_GI + 2 * HIDD + i] + r * ghp[2 * HIDD + i]);
      s_h[i] = (1.f - z) * n + z * h;
    }
  }
  __syncthreads();
  if (blk == 0) {  // persist h_new(s) -> buf np
    ((float4*)(ws + OFF_H + np * HIDD))[tid] = ((const float4*)s_h)[tid];
  }

  if (blk >= KL_GH0) {  // ---- gh(s+1) -> GH buf np ----
    if (s + 1 >= NSTEPS || done) return;
    const float4* h4 = (const float4*)s_h;
    float4 b0 = h4[lane], b1 = h4[lane + 64], b2 = h4[lane + 128], b3 = h4[lane + 192];
    const int wid = (blk - KL_GH0) * 4 + wave;
#pragma unroll
    for (int k = 0; k < 4; ++k) {
      const int r = wid + 768 * k;
      float v = wdot1024(Whh + (size_t)r * HIDD, lane, b0, b1, b2, b3) + bhh[r];
      if (lane == 0) ws[OFF_GH + np * 3 * HIDD + r] = v;
    }
    return;
  }

  if (blk == KL_ATTN) {  // ---- attn for step s+1 ----
    if (s + 1 >= NSTEPS || done) return;
    __shared__ float s_sc[64], s_aw[64];
    const float4* h4 = (const float4*)s_h;
    float4 b0 = h4[lane], b1 = h4[lane + 64], b2 = h4[lane + 128], b3 = h4[lane + 192];
    for (int j = wave; j < SEQL; j += 4) {
      float v = wdot1024(ws + OFF_M + (size_t)j * HIDD, lane, b0, b1, b2, b3) + ws[OFF_T + j];
      if (lane == 0) s_sc[j] = v;
    }
    __syncthreads();
    if (tid < 64) {
      float v = (tid < SEQL) ? s_sc[tid] : -INFINITY;
      float mx = v;
#pragma unroll
      for (int o = 32; o > 0; o >>= 1) mx = fmaxf(mx, __shfl_xor(mx, o, 64));
      float e = (tid < SEQL) ? expf(v - mx) : 0.f;
      float smv = wred_sum(e);
      if (tid < SEQL) s_aw[tid] = e / smv;
    }
    __syncthreads();
    const float4* enc4 = (const float4*)enc;
    float4 acc = make_float4(0.f, 0.f, 0.f, 0.f);
    for (int j = 0; j < SEQL; ++j) {
      float a = s_aw[j];
      float4 ev = enc4[(size_t)j * (CTXD / 4) + tid];
      acc.x += a * ev.x; acc.y += a * ev.y; acc.z += a * ev.z; acc.w += a * ev.w;
    }
    ((float4*)(ws + OFF_CTX))[tid] = acc;
    return;
  }

  // ---- fp16 logits GEMV + per-wave online stats (m, sum, top-2) ----
  if (done) return;  // stats stay stale; unused since valid=false downstream
  __shared__ float sm[4], ssm[4], sv1[4], sv2[4];
  __shared__ int si1[4], si2[4];
  float hb[16];
  {
    const float4* h4 = (const float4*)s_h;
    float4 a = h4[lane * 2], b = h4[lane * 2 + 1];
    float4 c = h4[128 + lane * 2], d = h4[129 + lane * 2];
    hb[0] = a.x; hb[1] = a.y; hb[2] = a.z; hb[3] = a.w;
    hb[4] = b.x; hb[5] = b.y; hb[6] = b.z; hb[7] = b.w;
    hb[8] = c.x; hb[9] = c.y; hb[10] = c.z; hb[11] = c.w;
    hb[12] = d.x; hb[13] = d.y; hb[14] = d.z; hb[15] = d.w;
  }
  const __half* WvH = (const __half*)(ws + OFF_WVH);
  float* Lc = ws + OFF_L + (size_t)p * LPAD;
  float m = -INFINITY, sum = 0.f, v1 = -INFINITY, v2 = -INFINITY;
  int i1 = 0x7fffffff, i2 = 0x7fffffff;
  for (int row = blk * 4 + wave; row < VOCABSZ; row += NW_LOG) {
    const uint4* r4 = (const uint4*)(WvH + (size_t)row * HIDD);
    float acc = acc8(r4[lane], hb) + acc8(r4[lane + 64], hb + 8);
    float l = wred_sum(acc) + bv[row];
    if (lane == 0) Lc[row] = l;
    float mn = fmaxf(m, l);
    sum = ((m == -INFINITY) ? 0.f : sum * __expf(m - mn)) + __expf(l - mn);
    m = mn;
    if (beats(l, row, v1, i1)) { v2 = v1; i2 = i1; v1 = l; i1 = row; }
    else if (beats(l, row, v2, i2)) { v2 = l; i2 = row; }
  }
  if (lane == 0) {
    sm[wave] = m; ssm[wave] = sum;
    sv1[wave] = v1; si1[wave] = i1; sv2[wave] = v2; si2[wave] = i2;
  }
  __syncthreads();
  if (tid == 0) {
    float mm = sm[0], su = ssm[0], a1 = sv1[0], a2 = sv2[0];
    int b1 = si1[0], b2 = si2[0];
#pragma unroll
    for (int w = 1; w < 4; ++w) {
      float mn = fmaxf(mm, sm[w]);
      su = su * __expf(mm - mn) + ssm[w] * __expf(sm[w] - mn);
      mm = mn;
      top2_merge(a1, b1, a2, b2, sv1[w], si1[w], sv2[w], si2[w]);
    }
    float* st = ws + OFF_STATS + (size_t)blk * 8;
    st[0] = mm; st[1] = su;
    st[2] = a1; st[3] = __int_as_float(b1);
    st[4] = a2; st[5] = __int_as_float(b2);
  }
}

extern "C" void kernel_launch(void* const* d_in, const int* in_sizes, int n_in,
                              void* d_out, int out_size, void* d_ws, size_t ws_size,
                              hipStream_t stream) {
  const float* enc   = (const float*)d_in[0];
  const float* hid0  = (const float*)d_in[1];
  const float* E     = (const float*)d_in[2];
  const float* Winit = (const float*)d_in[3];
  const float* binit = (const float*)d_in[4];
  const float* Wa    = (const float*)d_in[5];
  const float* ba    = (const float*)d_in[6];
  const float* Wih   = (const float*)d_in[7];
  const float* Whh   = (const float*)d_in[8];
  const float* bih   = (const float*)d_in[9];
  const float* bhh   = (const float*)d_in[10];
  const float* Wv    = (const float*)d_in[11];
  const float* bv    = (const float*)d_in[12];
  float* out = (float*)d_out;
  float* ws  = (float*)d_ws;

  const int n4 = (VOCABSZ * HIDD) / 4;
  k_cvt<<<4096, NTHR, 0, stream>>>((const float4*)Wv, (uint2*)(ws + OFF_WVH), n4);
  k0_matM<<<dim3(16, 13), 1024, 0, stream>>>(ws, enc, Wa);
  k0_init<<<257, NTHR, 0, stream>>>(ws, enc, hid0, Winit, binit, ba);
  k_init2<<<769, NTHR, 0, stream>>>(ws, enc, Whh, bhh);
  for (int s = 0; s < NSTEPS; ++s) {
    k_pre<<<PRE_GRID, NTHR, 0, stream>>>(ws, E, Wih, bih, Wv, bv, out, s);
    k_logits<<<KL_GRID, NTHR, 0, stream>>>(ws, bv, enc, Whh, bhh, out, s);
  }
  k_pre<<<PRE_GRID_FIN, NTHR, 0, stream>>>(ws, E, Wih, bih, Wv, bv, out, NSTEPS);
}

// Round 13
// 1825.683 us; speedup vs baseline: 1.5250x; 1.1429x over previous
//
#include <hip/hip_runtime.h>
#include <hip/hip_fp16.h>
#include <cmath>

#define VOCABSZ 50257
#define EMBD 512
#define HIDD 1024
#define CTXD 1024
#define SEQL 50
#define NSTEPS 50
#define BOS_ID 1
#define EOS_ID 2

#define NTHR 256
#define NB_GI 768               // gi blocks (3072 rows, 1 row/wave)
#define NB_WR 64                // logp writer blocks
#define NB_LOG 832              // logits stats blocks (R9 proven optimum)
#define NW_LOG (NB_LOG * 4)     // row stride (waves)
#define NB_GHN 192              // gh-next blocks in k_logits (4 rows/wave)
// k_logits block roles
#define KL_ATTN NB_LOG                  // 832
#define KL_GH0 (NB_LOG + 1)             // 833..1024
#define KL_WR0 (NB_LOG + 1 + NB_GHN)    // 1025..1088
#define KL_GRID (KL_WR0 + NB_WR)        // 1089
// k_pre grids
#define PRE_GRID (NB_GI + 1)            // 769 (in-loop)
#define PRE_GRID_FIN (NB_GI + 1 + NB_WR)// 833 (epilogue)

#define LPAD 50304

// ws float offsets
#define OFF_M      0        // 50*1024 (M = enc @ Wa)
#define OFF_T      51200    // 64      (t_j = enc_j . ba)
#define OFF_H      51264    // 2*1024  (h_new(s) stored in buf (s+1)&1)
#define OFF_CTX    53312    // 1024
#define OFF_GI     54336    // 3072
#define OFF_GH     57408    // 2*3072  (gh(s) in buf s&1)
#define OFF_L      63552    // 2*50304 (logits of step s in buf s&1)
#define OFF_STATS  164160   // 832*8 (m,sum,v1,i1,v2,i2,pad,pad)
#define OFF_STATE  170816   // ints: emb[0..50] +0, done[0..50] +64; floats +128: logZ, +129 valid
#define OFF_WVH    171072   // fp16 Wv: 50257*1024 halves

__device__ __forceinline__ float wred_sum(float v) {
#pragma unroll
  for (int o = 32; o > 0; o >>= 1) v += __shfl_xor(v, o, 64);
  return v;
}

__device__ __forceinline__ float dot4(float4 a, float4 b) {
  return a.x * b.x + a.y * b.y + a.z * b.z + a.w * b.w;
}

__device__ __forceinline__ float wdot1024(const float* __restrict__ row, int lane,
                                          float4 b0, float4 b1, float4 b2, float4 b3) {
  const float4* r = (const float4*)row;
  float acc = dot4(r[lane], b0) + dot4(r[lane + 64], b1) +
              dot4(r[lane + 128], b2) + dot4(r[lane + 192], b3);
  return wred_sum(acc);
}

__device__ __forceinline__ bool beats(float v, int i, float v0, int i0) {
  return v > v0 || (v == v0 && i < i0);
}

__device__ __forceinline__ void top2_merge(float& v1, int& i1, float& v2, int& i2,
                                           float w1, int j1, float w2, int j2) {
  if (beats(w1, j1, v1, i1)) {
    float nv2; int ni2;
    if (beats(v1, i1, w2, j2)) { nv2 = v1; ni2 = i1; } else { nv2 = w2; ni2 = j2; }
    v1 = w1; i1 = j1; v2 = nv2; i2 = ni2;
  } else if (beats(w1, j1, v2, i2)) {
    v2 = w1; i2 = j1;
  }
}

__device__ __forceinline__ float acc8(uint4 a, const float* b) {
  const __half2* h = reinterpret_cast<const __half2*>(&a);
  float2 f0 = __half22float2(h[0]);
  float2 f1 = __half22float2(h[1]);
  float2 f2 = __half22float2(h[2]);
  float2 f3 = __half22float2(h[3]);
  return f0.x * b[0] + f0.y * b[1] + f1.x * b[2] + f1.y * b[3] +
         f2.x * b[4] + f2.y * b[5] + f3.x * b[6] + f3.y * b[7];
}

// ---------------- f32 -> f16 conversion (Wv) ----------------
__global__ void __launch_bounds__(NTHR)
k_cvt(const float4* __restrict__ src, uint2* __restrict__ dst, int n4) {
  int i = blockIdx.x * NTHR + threadIdx.x;
  const int stride = gridDim.x * NTHR;
  for (; i < n4; i += stride) {
    float4 v = src[i];
    __half2 a = __floats2half2_rn(v.x, v.y);
    __half2 b = __floats2half2_rn(v.z, v.w);
    uint2 u;
    u.x = *reinterpret_cast<unsigned*>(&a);
    u.y = *reinterpret_cast<unsigned*>(&b);
    dst[i] = u;
  }
}

// ---------------- K0a: M = enc @ Wa ----------------
__global__ void __launch_bounds__(1024)
k0_matM(float* __restrict__ ws, const float* __restrict__ enc,
        const float* __restrict__ Wa) {
  const int kc = blockIdx.x;
  const int jg = blockIdx.y;
  const int tid = threadIdx.x;
  const int w = tid >> 6, lane = tid & 63;
  const int jw = w & 3, q = w >> 2;
  const int j = jg * 4 + jw;
  const int k = kc * 64 + lane;
  __shared__ float s_red[16][64];
  float acc0 = 0.f, acc1 = 0.f, acc2 = 0.f, acc3 = 0.f;
  if (j < SEQL) {
    const float4* e4 = (const float4*)(enc + (size_t)j * CTXD);
    const float* Wc = Wa + k;
    for (int c4 = q * 64; c4 < q * 64 + 64; ++c4) {
      float4 e = e4[c4];
      const float* wp = Wc + (size_t)(c4 * 4) * HIDD;
      acc0 += e.x * wp[0];
      acc1 += e.y * wp[HIDD];
      acc2 += e.z * wp[2 * HIDD];
      acc3 += e.w * wp[3 * HIDD];
    }
  }
  s_red[w][lane] = acc0 + acc1 + acc2 + acc3;
  __syncthreads();
  if (q == 0 && j < SEQL) {
    float v = s_red[jw][lane] + s_red[4 + jw][lane] +
              s_red[8 + jw][lane] + s_red[12 + jw][lane];
    ws[OFF_M + (size_t)j * HIDD + k] = v;
  }
}

// ---------------- K0b: t = enc@ba, h0, state init ----------------
__global__ void __launch_bounds__(NTHR)
k0_init(float* __restrict__ ws, const float* __restrict__ enc,
        const float* __restrict__ hid0, const float* __restrict__ Winit,
        const float* __restrict__ binit, const float* __restrict__ ba) {
  const int blk = blockIdx.x, tid = threadIdx.x;
  const int wave = tid >> 6, lane = tid & 63;
  if (blk == 0) {
    const float4* b4 = (const float4*)ba;
    float4 b0 = b4[lane], b1 = b4[lane + 64], b2 = b4[lane + 128], b3 = b4[lane + 192];
    for (int j = wave; j < SEQL; j += 4) {
      float v = wdot1024(enc + (size_t)j * CTXD, lane, b0, b1, b2, b3);
      if (lane == 0) ws[OFF_T + j] = v;
    }
    if (tid == 0) {
      int* st_emb = (int*)(ws + OFF_STATE);
      st_emb[0] = BOS_ID;
      st_emb[64] = 0;  // done[0]
    }
  } else {
    const float4* h4 = (const float4*)hid0;
    float4 b0 = h4[lane], b1 = h4[lane + 64], b2 = h4[lane + 128], b3 = h4[lane + 192];
    int row = (blk - 1) * 4 + wave;
    float v = wdot1024(Winit + (size_t)row * CTXD, lane, b0, b1, b2, b3) + binit[row];
    if (lane == 0) ws[OFF_H + row] = v;  // h0 -> buf 0
  }
}

// ---------------- attention from ws[hoff] (one block) ----------------
__device__ __forceinline__ void attn_from(float* __restrict__ ws, int hoff,
                                          const float* __restrict__ enc,
                                          int tid, int wave, int lane,
                                          float* s_h, float* s_sc, float* s_aw) {
  ((float4*)s_h)[tid] = ((const float4*)(ws + hoff))[tid];
  __syncthreads();
  const float4* h4 = (const float4*)s_h;
  float4 b0 = h4[lane], b1 = h4[lane + 64], b2 = h4[lane + 128], b3 = h4[lane + 192];
  for (int j = wave; j < SEQL; j += 4) {
    float v = wdot1024(ws + OFF_M + (size_t)j * HIDD, lane, b0, b1, b2, b3) + ws[OFF_T + j];
    if (lane == 0) s_sc[j] = v;
  }
  __syncthreads();
  if (tid < 64) {
    float v = (tid < SEQL) ? s_sc[tid] : -INFINITY;
    float mx = v;
#pragma unroll
    for (int o = 32; o > 0; o >>= 1) mx = fmaxf(mx, __shfl_xor(mx, o, 64));
    float e = (tid < SEQL) ? expf(v - mx) : 0.f;
    float sm = wred_sum(e);
    if (tid < SEQL) s_aw[tid] = e / sm;
  }
  __syncthreads();
  const float4* enc4 = (const float4*)enc;
  float4 acc = make_float4(0.f, 0.f, 0.f, 0.f);
  for (int j = 0; j < SEQL; ++j) {
    float a = s_aw[j];
    float4 ev = enc4[(size_t)j * (CTXD / 4) + tid];
    acc.x += a * ev.x; acc.y += a * ev.y; acc.z += a * ev.z; acc.w += a * ev.w;
  }
  ((float4*)(ws + OFF_CTX))[tid] = acc;
}

// ---------------- K0c: ctx_0 + gh(0) into GH buf 0 ----------------
__global__ void __launch_bounds__(NTHR)
k_init2(float* __restrict__ ws, const float* __restrict__ enc,
        const float* __restrict__ Whh, const float* __restrict__ bhh) {
  const int blk = blockIdx.x, tid = threadIdx.x;
  const int wave = tid >> 6, lane = tid & 63;
  if (blk == 0) {
    __shared__ float s_h[HIDD];
    __shared__ float s_sc[64], s_aw[64];
    attn_from(ws, OFF_H, enc, tid, wave, lane, s_h, s_sc, s_aw);
  } else {
    const float4* h4 = (const float4*)(ws + OFF_H);
    float4 b0 = h4[lane], b1 = h4[lane + 64], b2 = h4[lane + 128], b3 = h4[lane + 192];
    const int r = (blk - 1) * 4 + wave;
    float v = wdot1024(Whh + (size_t)r * HIDD, lane, b0, b1, b2, b3) + bhh[r];
    if (lane == 0) ws[OFF_GH + r] = v;
  }
}

// ---------------- k_pre(s): combine stats(s-1) -> state/outputs; gi(s) ----------------
__global__ void __launch_bounds__(NTHR)
k_pre(float* __restrict__ ws, const float* __restrict__ E,
      const float* __restrict__ Wih, const float* __restrict__ bih,
      const float* __restrict__ Wv, const float* __restrict__ bv,
      float* __restrict__ out, int s) {
  const int blk = blockIdx.x, tid = threadIdx.x;
  const int wave = tid >> 6, lane = tid & 63;
  int* st_emb = (int*)(ws + OFF_STATE);
  int* st_done = st_emb + 64;
  const int hoff = OFF_H + (s & 1) * HIDD;  // h_new(s-1)

  const bool is_gi = (blk < NB_GI);
  const bool is_state = (blk == NB_GI);
  const bool is_writer = (blk > NB_GI);
  if (is_gi && s >= NSTEPS) return;
  if ((is_state || is_writer) && s == 0) return;

  int emb_s = 0, D_s = 0, gidx = -1;
  float logZ = 0.f;
  bool valid = false, eos = false;

  if (s > 0) {
    __shared__ float rm[NTHR], rs_[NTHR], rv1[NTHR], rv2[NTHR];
    __shared__ int ri1[NTHR], ri2[NTHR];
    __shared__ float s_ex[2];
    float m = -INFINITY, su = 0.f, v1 = -INFINITY, v2 = -INFINITY;
    int i1 = 0x7fffffff, i2 = 0x7fffffff;
    const float4* sb = (const float4*)(ws + OFF_STATS);
    for (int q = tid; q < NB_LOG; q += NTHR) {
      float4 A = sb[q * 2];
      float4 B = sb[q * 2 + 1];
      float mn = fmaxf(m, A.x);
      su = ((m == -INFINITY) ? 0.f : su * __expf(m - mn)) + A.y * __expf(A.x - mn);
      m = mn;
      top2_merge(v1, i1, v2, i2, A.z, __float_as_int(A.w), B.x, __float_as_int(B.y));
    }
    rm[tid] = m; rs_[tid] = su; rv1[tid] = v1; ri1[tid] = i1; rv2[tid] = v2; ri2[tid] = i2;
    __syncthreads();
    for (int st = 128; st > 0; st >>= 1) {
      if (tid < st) {
        float m2 = rm[tid + st], s2 = rs_[tid + st];
        float mn = fmaxf(rm[tid], m2);
        rs_[tid] = rs_[tid] * __expf(rm[tid] - mn) + s2 * __expf(m2 - mn);
        rm[tid] = mn;
        float a1 = rv1[tid], a2 = rv2[tid];
        int b1 = ri1[tid], b2 = ri2[tid];
        top2_merge(a1, b1, a2, b2, rv1[tid + st], ri1[tid + st], rv2[tid + st], ri2[tid + st]);
        rv1[tid] = a1; ri1[tid] = b1; rv2[tid] = a2; ri2[tid] = b2;
      }
      __syncthreads();
    }
    const int fi1 = ri1[0], fi2 = ri2[0];
    // exact f32 recompute of the two candidates (fp16 argmax protection)
    if (wave < 2) {
      const float4* h4 = (const float4*)(ws + hoff);
      float4 b0 = h4[lane], b1 = h4[lane + 64], b2 = h4[lane + 128], b3 = h4[lane + 192];
      const int r = (wave == 0) ? fi1 : fi2;
      float v = wdot1024(Wv + (size_t)r * HIDD, lane, b0, b1, b2, b3) + bv[r];
      if (lane == 0) s_ex[wave] = v;
    }
    __syncthreads();
    gidx = beats(s_ex[1], fi2, s_ex[0], fi1) ? fi2 : fi1;
    logZ = rm[0] + logf(rs_[0]);
    const int Dp = st_done[s - 1];
    valid = (Dp == 0);
    eos = (gidx == EOS_ID);
    D_s = Dp | (eos ? 1 : 0);
    emb_s = (valid && !eos) ? gidx : st_emb[s - 1];
  } else {
    emb_s = st_emb[0];
  }

  if (is_gi) {
    if (D_s) return;  // h frozen -> gi unused
    const int r = blk * 4 + wave;
    const float4* e4 = (const float4*)(E + (size_t)emb_s * EMBD);
    float4 eb0 = e4[lane], eb1 = e4[lane + 64];
    const float4* c4 = (const float4*)(ws + OFF_CTX);
    float4 cb0 = c4[lane], cb1 = c4[lane + 64], cb2 = c4[lane + 128], cb3 = c4[lane + 192];
    const float* rowp = Wih + (size_t)r * (EMBD + CTXD);
    const float4* re = (const float4*)rowp;
    const float4* rc = (const float4*)(rowp + EMBD);
    float acc = dot4(re[lane], eb0) + dot4(re[lane + 64], eb1) +
                dot4(rc[lane], cb0) + dot4(rc[lane + 64], cb1) +
                dot4(rc[lane + 128], cb2) + dot4(rc[lane + 192], cb3);
    float v = wred_sum(acc) + bih[r];
    if (lane == 0) ws[OFF_GI + r] = v;
  } else if (is_state) {
    if (tid == 0) {
      out[s - 1] = (valid && !eos) ? (float)gidx : -1.f;
      out[NSTEPS + (size_t)NSTEPS * VOCABSZ + (s - 1)] = valid ? 1.f : 0.f;
      st_emb[s] = emb_s;
      st_done[s] = D_s;
      ws[OFF_STATE + 128] = logZ;
      ws[OFF_STATE + 129] = valid ? 1.f : 0.f;
    }
  } else {  // epilogue logp writers for step s-1
    const float* Lp = ws + OFF_L + (size_t)((s - 1) & 1) * LPAD;
    float* logp = out + NSTEPS + (size_t)(s - 1) * VOCABSZ;
    for (int i = (blk - NB_GI - 1) * NTHR + tid; i < VOCABSZ; i += NB_WR * NTHR)
      logp[i] = valid ? (Lp[i] - logZ) : 0.f;
  }
}

// ---------------- k_logits(s): GRU -> h_new(s); fp16 GEMV + stats; attn; gh; logp(s-1) writers ----------------
__global__ void __launch_bounds__(NTHR)
k_logits(float* __restrict__ ws, const float* __restrict__ bv,
         const float* __restrict__ enc, const float* __restrict__ Whh,
         const float* __restrict__ bhh, float* __restrict__ out, int s) {
  const int blk = blockIdx.x, tid = threadIdx.x;
  const int wave = tid >> 6, lane = tid & 63;
  const int p = s & 1, np = p ^ 1;

  // ---- logp writers for step s-1 (no GRU needed) ----
  if (blk >= KL_WR0) {
    if (s == 0) return;
    const float logZ = ws[OFF_STATE + 128];
    const bool valid = ws[OFF_STATE + 129] != 0.f;
    const float* Lp = ws + OFF_L + (size_t)np * LPAD;  // (s-1)&1 == np
    float* logp = out + NSTEPS + (size_t)(s - 1) * VOCABSZ;
    for (int i = (blk - KL_WR0) * NTHR + tid; i < VOCABSZ; i += NB_WR * NTHR)
      logp[i] = valid ? (Lp[i] - logZ) : 0.f;
    return;
  }

  __shared__ float s_h[HIDD];
  const int* st_emb = (const int*)(ws + OFF_STATE);
  const int done = st_emb[64 + s];

  // fused pointwise GRU (redundant per block): h_new(s) from h_new(s-1), gi(s), gh(s)
  const float* hp = ws + OFF_H + p * HIDD;
  const float* ghp = ws + OFF_GH + p * 3 * HIDD;
#pragma unroll
  for (int it = 0; it < HIDD / NTHR; ++it) {
    const int i = tid + it * NTHR;
    float h = hp[i];
    if (done) {
      s_h[i] = h;
    } else {
      float r = 1.f / (1.f + __expf(-(ws[OFF_GI + i] + ghp[i])));
      float z = 1.f / (1.f + __expf(-(ws[OFF_GI + HIDD + i] + ghp[HIDD + i])));
      float n = tanhf(ws[OFF_GI + 2 * HIDD + i] + r * ghp[2 * HIDD + i]);
      s_h[i] = (1.f - z) * n + z * h;
    }
  }
  __syncthreads();
  if (blk == 0) {  // persist h_new(s) -> buf np
    ((float4*)(ws + OFF_H + np * HIDD))[tid] = ((const float4*)s_h)[tid];
  }

  if (blk >= KL_GH0) {  // ---- gh(s+1) -> GH buf np ----
    if (s + 1 >= NSTEPS || done) return;
    const float4* h4 = (const float4*)s_h;
    float4 b0 = h4[lane], b1 = h4[lane + 64], b2 = h4[lane + 128], b3 = h4[lane + 192];
    const int wid = (blk - KL_GH0) * 4 + wave;
#pragma unroll
    for (int k = 0; k < 4; ++k) {
      const int r = wid + 768 * k;
      float v = wdot1024(Whh + (size_t)r * HIDD, lane, b0, b1, b2, b3) + bhh[r];
      if (lane == 0) ws[OFF_GH + np * 3 * HIDD + r] = v;
    }
    return;
  }

  if (blk == KL_ATTN) {  // ---- attn for step s+1 ----
    if (s + 1 >= NSTEPS || done) return;
    __shared__ float s_sc[64], s_aw[64];
    const float4* h4 = (const float4*)s_h;
    float4 b0 = h4[lane], b1 = h4[lane + 64], b2 = h4[lane + 128], b3 = h4[lane + 192];
    for (int j = wave; j < SEQL; j += 4) {
      float v = wdot1024(ws + OFF_M + (size_t)j * HIDD, lane, b0, b1, b2, b3) + ws[OFF_T + j];
      if (lane == 0) s_sc[j] = v;
    }
    __syncthreads();
    if (tid < 64) {
      float v = (tid < SEQL) ? s_sc[tid] : -INFINITY;
      float mx = v;
#pragma unroll
      for (int o = 32; o > 0; o >>= 1) mx = fmaxf(mx, __shfl_xor(mx, o, 64));
      float e = (tid < SEQL) ? expf(v - mx) : 0.f;
      float smv = wred_sum(e);
      if (tid < SEQL) s_aw[tid] = e / smv;
    }
    __syncthreads();
    const float4* enc4 = (const float4*)enc;
    float4 acc = make_float4(0.f, 0.f, 0.f, 0.f);
    for (int j = 0; j < SEQL; ++j) {
      float a = s_aw[j];
      float4 ev = enc4[(size_t)j * (CTXD / 4) + tid];
      acc.x += a * ev.x; acc.y += a * ev.y; acc.z += a * ev.z; acc.w += a * ev.w;
    }
    ((float4*)(ws + OFF_CTX))[tid] = acc;
    return;
  }

  // ---- fp16 logits GEMV + per-wave online stats (m, sum, top-2) ----
  if (done) return;  // stats stay stale; unused since valid=false downstream
  __shared__ float sm[4], ssm[4], sv1[4], sv2[4];
  __shared__ int si1[4], si2[4];
  float hb[16];
  {
    const float4* h4 = (const float4*)s_h;
    float4 a = h4[lane * 2], b = h4[lane * 2 + 1];
    float4 c = h4[128 + lane * 2], d = h4[129 + lane * 2];
    hb[0] = a.x; hb[1] = a.y; hb[2] = a.z; hb[3] = a.w;
    hb[4] = b.x; hb[5] = b.y; hb[6] = b.z; hb[7] = b.w;
    hb[8] = c.x; hb[9] = c.y; hb[10] = c.z; hb[11] = c.w;
    hb[12] = d.x; hb[13] = d.y; hb[14] = d.z; hb[15] = d.w;
  }
  const __half* WvH = (const __half*)(ws + OFF_WVH);
  float* Lc = ws + OFF_L + (size_t)p * LPAD;
  float m = -INFINITY, sum = 0.f, v1 = -INFINITY, v2 = -INFINITY;
  int i1 = 0x7fffffff, i2 = 0x7fffffff;
  for (int row = blk * 4 + wave; row < VOCABSZ; row += NW_LOG) {
    const uint4* r4 = (const uint4*)(WvH + (size_t)row * HIDD);
    float acc = acc8(r4[lane], hb) + acc8(r4[lane + 64], hb + 8);
    float l = wred_sum(acc) + bv[row];
    if (lane == 0) Lc[row] = l;
    float mn = fmaxf(m, l);
    sum = ((m == -INFINITY) ? 0.f : sum * __expf(m - mn)) + __expf(l - mn);
    m = mn;
    if (beats(l, row, v1, i1)) { v2 = v1; i2 = i1; v1 = l; i1 = row; }
    else if (beats(l, row, v2, i2)) { v2 = l; i2 = row; }
  }
  if (lane == 0) {
    sm[wave] = m; ssm[wave] = sum;
    sv1[wave] = v1; si1[wave] = i1; sv2[wave] = v2; si2[wave] = i2;
  }
  __syncthreads();
  if (tid == 0) {
    float mm = sm[0], su = ssm[0], a1 = sv1[0], a2 = sv2[0];
    int b1 = si1[0], b2 = si2[0];
#pragma unroll
    for (int w = 1; w < 4; ++w) {
      float mn = fmaxf(mm, sm[w]);
      su = su * __expf(mm - mn) + ssm[w] * __expf(sm[w] - mn);
      mm = mn;
      top2_merge(a1, b1, a2, b2, sv1[w], si1[w], sv2[w], si2[w]);
    }
    float* st = ws + OFF_STATS + (size_t)blk * 8;
    st[0] = mm; st[1] = su;
    st[2] = a1; st[3] = __int_as_float(b1);
    st[4] = a2; st[5] = __int_as_float(b2);
  }
}

extern "C" void kernel_launch(void* const* d_in, const int* in_sizes, int n_in,
                              void* d_out, int out_size, void* d_ws, size_t ws_size,
                              hipStream_t stream) {
  const float* enc   = (const float*)d_in[0];
  const float* hid0  = (const float*)d_in[1];
  const float* E     = (const float*)d_in[2];
  const float* Winit = (const float*)d_in[3];
  const float* binit = (const float*)d_in[4];
  const float* Wa    = (const float*)d_in[5];
  const float* ba    = (const float*)d_in[6];
  const float* Wih   = (const float*)d_in[7];
  const float* Whh   = (const float*)d_in[8];
  const float* bih   = (const float*)d_in[9];
  const float* bhh   = (const float*)d_in[10];
  const float* Wv    = (const float*)d_in[11];
  const float* bv    = (const float*)d_in[12];
  float* out = (float*)d_out;
  float* ws  = (float*)d_ws;

  const int n4 = (VOCABSZ * HIDD) / 4;
  k_cvt<<<4096, NTHR, 0, stream>>>((const float4*)Wv, (uint2*)(ws + OFF_WVH), n4);
  k0_matM<<<dim3(16, 13), 1024, 0, stream>>>(ws, enc, Wa);
  k0_init<<<257, NTHR, 0, stream>>>(ws, enc, hid0, Winit, binit, ba);
  k_init2<<<769, NTHR, 0, stream>>>(ws, enc, Whh, bhh);
  for (int s = 0; s < NSTEPS; ++s) {
    k_pre<<<PRE_GRID, NTHR, 0, stream>>>(ws, E, Wih, bih, Wv, bv, out, s);
    k_logits<<<KL_GRID, NTHR, 0, stream>>>(ws, bv, enc, Whh, bhh, out, s);
  }
  k_pre<<<PRE_GRID_FIN, NTHR, 0, stream>>>(ws, E, Wih, bih, Wv, bv, out, NSTEPS);
}